// Round 1
// baseline (177.406 us; speedup 1.0000x reference)
//
#include <hip/hip_runtime.h>
#include <hip/hip_bf16.h>

// CrossNATBlock2D: B=1, H=W=128, C=128, HEADS=4, HD=32, K=7  (fp32 I/O)
// R18: latency-bound restructure. k_fam split into k_attn + k_mlp; all heavy
// kernels moved to 16-px / 256-thread blocks (grid 1024 = 4 independent
// blocks/CU, decorrelated phases) instead of 32-px/512-thr (2/CU lockstep).
// k_attn time-shares one LDS buffer for K then V (V prefetched to regs, written
// back after the post-QK barrier; softmax hides the drain). x1 intermediate is
// fp32 in d_out (in-place for k_mlp) -> fp32 residual path, xbo copy removed.

#define N_PIX 16384
#define C 128
#define HEADS 4
#define HD 32
#define HW 128

typedef __hip_bfloat16 bf16;
typedef __attribute__((ext_vector_type(8))) short bf16x8;
typedef __attribute__((ext_vector_type(4))) float f32x4;

__device__ __forceinline__ short f2bs(float f) {
    bf16 h = __float2bfloat16(f);
    return (short)__bfloat16_as_ushort(h);
}
__device__ __forceinline__ float bs2f(short s) {
    __hip_bfloat16_raw r; r.x = (unsigned short)s;
    return __bfloat162float(__hip_bfloat16(r));
}
__device__ __forceinline__ float gelu_f(float v) {
    const float z = 1.5957691216f * (v + 0.044715f * v * v * v);
    return v / (1.f + __expf(-z));
}
__device__ __forceinline__ unsigned int pack2(float a, float b) {
    return (unsigned int)(unsigned short)f2bs(a) |
           ((unsigned int)(unsigned short)f2bs(b) << 16);
}

// ---------- kernel 0: convert weights fp32 -> bf16 into ws ----------
__global__ __launch_bounds__(256) void k_wconv(
    const float* __restrict__ qv_w, const float* __restrict__ k_w,
    const float* __restrict__ proj_w, const float* __restrict__ fc1_w,
    const float* __restrict__ fc2_w,
    short* __restrict__ wqv, short* __restrict__ wk, short* __restrict__ wproj,
    short* __restrict__ wfc1, short* __restrict__ wfc2) {
    const int i = blockIdx.x * 256 + threadIdx.x;
    if (i < 32768) wqv[i] = f2bs(qv_w[i]);
    if (i < 16384) { wk[i] = f2bs(k_w[i]); wproj[i] = f2bs(proj_w[i]); }
    if (i < 65536) { wfc1[i] = f2bs(fc1_w[i]); wfc2[i] = f2bs(fc2_w[i]); }
}

// ---------- kernel 1: LN1 + QV GEMM + K proj, 16 px/block, 256 thr ----------
__global__ __launch_bounds__(256, 4) void k_qkv(
    const float* __restrict__ x, const float* __restrict__ y,
    const short* __restrict__ wqv, const float* __restrict__ qv_b,
    const short* __restrict__ wk, const float* __restrict__ k_b,
    const float* __restrict__ n1_w, const float* __restrict__ n1_b,
    bf16* __restrict__ qb, bf16* __restrict__ vb, bf16* __restrict__ kb) {
    __shared__ float xr[16][132];
    __shared__ short xn[16][136];
    __shared__ short yl[16][136];
    __shared__ float muA[16], riA[16];
    const int t = threadIdx.x;
    const int pix0 = (blockIdx.x & 7) * 2048 + (blockIdx.x >> 3) * 16;
    for (int e = t; e < 512; e += 256) {           // 16 rows x 32 float4 groups
        const int r = e >> 5, c4 = (e & 31) * 4;
        const float4 xv = *(const float4*)(x + (size_t)(pix0 + r) * C + c4);
        *(float4*)&xr[r][c4] = xv;
        const float4 yv = *(const float4*)(y + (size_t)(pix0 + r) * C + c4);
        uint2 yp; yp.x = pack2(yv.x, yv.y); yp.y = pack2(yv.z, yv.w);
        *(uint2*)&yl[r][c4] = yp;
    }
    __syncthreads();
    if (t < 128) {
        const int r = t >> 3, s = t & 7;
        float sm = 0.f, sq = 0.f;
        for (int i = 0; i < 16; i++) { float v = xr[r][s * 16 + i]; sm += v; sq += v * v; }
        for (int m = 1; m < 8; m <<= 1) { sm += __shfl_xor(sm, m, 64); sq += __shfl_xor(sq, m, 64); }
        if (s == 0) {
            const float mu = sm * (1.f / 128.f);
            const float var = sq * (1.f / 128.f) - mu * mu;
            muA[r] = mu; riA[r] = rsqrtf(var + 1e-5f);
        }
    }
    __syncthreads();
    for (int e = t; e < 2048; e += 256) {
        const int r = e >> 7, c = e & 127;
        xn[r][c] = f2bs((xr[r][c] - muA[r]) * riA[r] * n1_w[c] + n1_b[c]);
    }
    __syncthreads();
    const int wave = t >> 6, lane = t & 63, quad = lane >> 4, l15 = lane & 15;
    const float scale = 0.1767766952966369f;   // 1/sqrt(32)
    // qv GEMM: M=16, 16 n-tiles over 4 waves
    {
        bf16x8 aA[4];
#pragma unroll
        for (int kt = 0; kt < 4; kt++)
            aA[kt] = *(const bf16x8*)&xn[l15][kt * 32 + quad * 8];
#pragma unroll
        for (int s = 0; s < 4; s++) {
            const int n = (wave * 4 + s) * 16 + l15;
            f32x4 acc = {0.f, 0.f, 0.f, 0.f};
#pragma unroll
            for (int kt = 0; kt < 4; kt++) {
                bf16x8 b = *(const bf16x8*)&wqv[n * C + kt * 32 + quad * 8];
                acc = __builtin_amdgcn_mfma_f32_16x16x32_bf16(aA[kt], b, acc, 0, 0, 0);
            }
            const float bias = qv_b[n];
#pragma unroll
            for (int r = 0; r < 4; r++) {
                const int m = quad * 4 + r;
                const float v = acc[r] + bias;
                if (n < C) qb[(size_t)(pix0 + m) * C + n] = __float2bfloat16(v * scale);
                else       vb[(size_t)(pix0 + m) * C + (n - C)] = __float2bfloat16(v);
            }
        }
    }
    // k GEMM: 8 n-tiles over 4 waves, 2 each, interleaved accumulators
    {
        bf16x8 aY[4];
#pragma unroll
        for (int kt = 0; kt < 4; kt++)
            aY[kt] = *(const bf16x8*)&yl[l15][kt * 32 + quad * 8];
        const int n0 = (wave * 2) * 16 + l15, n1 = (wave * 2 + 1) * 16 + l15;
        f32x4 a0 = {0.f, 0.f, 0.f, 0.f}, a1 = {0.f, 0.f, 0.f, 0.f};
#pragma unroll
        for (int kt = 0; kt < 4; kt++) {
            bf16x8 b0 = *(const bf16x8*)&wk[n0 * C + kt * 32 + quad * 8];
            bf16x8 b1 = *(const bf16x8*)&wk[n1 * C + kt * 32 + quad * 8];
            a0 = __builtin_amdgcn_mfma_f32_16x16x32_bf16(aY[kt], b0, a0, 0, 0, 0);
            a1 = __builtin_amdgcn_mfma_f32_16x16x32_bf16(aY[kt], b1, a1, 0, 0, 0);
        }
        const float b0s = k_b[n0], b1s = k_b[n1];
#pragma unroll
        for (int r = 0; r < 4; r++) {
            const int m = quad * 4 + r;
            kb[(size_t)(pix0 + m) * C + n0] = __float2bfloat16(a0[r] + b0s);
            kb[(size_t)(pix0 + m) * C + n1] = __float2bfloat16(a1[r] + b1s);
        }
    }
}

// ---------- kernel 2: attention + proj + residual -> x1 (fp32, in d_out) ----
// 4x4 tile (16 px), 256 thr, wave = head. Union 10x10=100 rows, staged as 112
// (rows >=100 duplicate row 99). K then V time-share U; V prefetched to regs.
__global__ __launch_bounds__(256, 3) void k_attn(
    const bf16* __restrict__ qb, const bf16* __restrict__ kb,
    const bf16* __restrict__ vb, const float* __restrict__ rpb,
    const float* __restrict__ x,
    const short* __restrict__ wproj, const float* __restrict__ proj_b,
    float* __restrict__ out) {
    __shared__ short U[112 * 132];     // 29568 B: K union, then V union
    __shared__ short Pb[64 * 120];     // 15360 B: P, [head*16+px][120]
    __shared__ short aoL[16 * 136];    // 4352 B
    const int t = threadIdx.x;
    const int wave = t >> 6, lane = t & 63, quad = lane >> 4, l15 = lane & 15;
    const int h = wave;
    const int tile = (blockIdx.x & 7) * 128 + (blockIdx.x >> 3);   // XCD swizzle
    const int i0 = (tile >> 5) * 4, j0 = (tile & 31) * 4;
    const int rs = min(max(i0 - 3, 0), 118);
    const int cs = min(max(j0 - 3, 0), 118);
    // ---- prefetch Q frag + fp32 x residual ----
    const int pA = (i0 + (l15 >> 2)) * HW + j0 + (l15 & 3);
    const bf16x8 aQ = *(const bf16x8*)(qb + (size_t)pA * C + h * HD + quad * 8);
    const int nR0 = h * 16 + l15, nR1 = (h + 4) * 16 + l15;
    float xres0[4], xres1[4];
#pragma unroll
    for (int r = 0; r < 4; r++) {
        const int m = quad * 4 + r;
        const int p = (i0 + (m >> 2)) * HW + j0 + (m & 3);
        xres0[r] = x[(size_t)p * C + nR0];
        xres1[r] = x[(size_t)p * C + nR1];
    }
    // ---- stage K -> LDS; V -> regs (latency hides under QK below) ----
    uint4 vst[7];
#pragma unroll
    for (int it = 0; it < 7; ++it) {
        const int u = t + it * 256;
        const int r = u >> 4, seg = u & 15;
        const int sr = min(r, 99);
        const size_t g = (size_t)((rs + sr / 10) * HW + cs + sr % 10) * C + seg * 8;
        *(uint4*)&U[r * 132 + seg * 8] = *(const uint4*)(kb + g);
        vst[it] = *(const uint4*)(vb + g);
    }
    __syncthreads();
    // ---- QK^T: 7 neighbor tiles ----
    f32x4 S[7];
#pragma unroll
    for (int nt = 0; nt < 7; nt++) {
        const bf16x8 bK = *(const bf16x8*)&U[(nt * 16 + l15) * 132 + h * HD + quad * 8];
        f32x4 z = {0.f, 0.f, 0.f, 0.f};
        S[nt] = __builtin_amdgcn_mfma_f32_16x16x32_bf16(aQ, bK, z, 0, 0, 0);
    }
    __syncthreads();           // all K reads done
    // ---- V regs -> LDS (overwrites K); drain hides under softmax ----
#pragma unroll
    for (int it = 0; it < 7; ++it) {
        const int u = t + it * 256;
        const int r = u >> 4, seg = u & 15;
        *(uint4*)&U[r * 132 + seg * 8] = vst[it];
    }
    // ---- softmax (bias + mask + row max/sum) ----
    const float* rpbh = rpb + h * 169;
    int aiA[7], ajA[7];
#pragma unroll
    for (int nt = 0; nt < 7; nt++) {
        const int nb = nt * 16 + l15;
        aiA[nt] = rs + nb / 10;
        ajA[nt] = cs + nb % 10;
    }
    float smx[4];
#pragma unroll
    for (int r = 0; r < 4; r++) {
        const int m = quad * 4 + r;
        const int i = i0 + (m >> 2), j = j0 + (m & 3);
        const int shi = min(max(i - 3, 0), 121);
        const int swj = min(max(j - 3, 0), 121);
        float best = -1e30f;
#pragma unroll
        for (int nt = 0; nt < 7; nt++) {
            const int nb = nt * 16 + l15;
            const int ai = aiA[nt], aj = ajA[nt];
            const bool valid = (nb < 100) & (ai >= shi) & (ai <= shi + 6) & (aj >= swj) & (aj <= swj + 6);
            const int ri = min(max(ai - i + 6, 0), 12);
            const int rj = min(max(aj - j + 6, 0), 12);
            const float v = valid ? (S[nt][r] + rpbh[ri * 13 + rj]) : -1e30f;
            S[nt][r] = v;
            best = fmaxf(best, v);
        }
        for (int msk = 1; msk < 16; msk <<= 1) best = fmaxf(best, __shfl_xor(best, msk, 64));
        float s = 0.f;
#pragma unroll
        for (int nt = 0; nt < 7; nt++) {
            const float e = __expf(S[nt][r] - best);
            S[nt][r] = e;
            s += e;
        }
        for (int msk = 1; msk < 16; msk <<= 1) s += __shfl_xor(s, msk, 64);
        smx[r] = 1.f / s;
    }
    // ---- P write (own wave rows only) ----
#pragma unroll
    for (int r = 0; r < 4; r++) {
        short* prow = &Pb[(h * 16 + quad * 4 + r) * 120];
#pragma unroll
        for (int nt = 0; nt < 7; nt++) prow[nt * 16 + l15] = f2bs(S[nt][r] * smx[r]);
    }
    __syncthreads();           // V visible to all; P same-wave ordering suffices
    // ---- PV: kt 0..2 full; kt=3 tail with A,B zeroed for k>=112 ----
    f32x4 O0 = {0.f, 0.f, 0.f, 0.f}, O1 = {0.f, 0.f, 0.f, 0.f};
#pragma unroll
    for (int kt = 0; kt < 3; kt++) {
        const bf16x8 aP = *(const bf16x8*)&Pb[(h * 16 + l15) * 120 + kt * 32 + quad * 8];
#pragma unroll
        for (int nt2 = 0; nt2 < 2; nt2++) {
            const int ch = h * HD + nt2 * 16 + l15;
            const int base = (kt * 32 + quad * 8) * 132 + ch;
            bf16x8 bV;
#pragma unroll
            for (int jj = 0; jj < 8; jj++) bV[jj] = U[base + jj * 132];
            if (nt2 == 0) O0 = __builtin_amdgcn_mfma_f32_16x16x32_bf16(aP, bV, O0, 0, 0, 0);
            else          O1 = __builtin_amdgcn_mfma_f32_16x16x32_bf16(aP, bV, O1, 0, 0, 0);
        }
    }
    {   // tail: k = 96..127; only quads 0,1 (k<112) carry data (P masked >=100)
        bf16x8 aP = {0, 0, 0, 0, 0, 0, 0, 0};
        if (quad < 2) aP = *(const bf16x8*)&Pb[(h * 16 + l15) * 120 + 96 + quad * 8];
#pragma unroll
        for (int nt2 = 0; nt2 < 2; nt2++) {
            const int ch = h * HD + nt2 * 16 + l15;
            bf16x8 bV = {0, 0, 0, 0, 0, 0, 0, 0};
            if (quad < 2) {
                const int base = (96 + quad * 8) * 132 + ch;
#pragma unroll
                for (int jj = 0; jj < 8; jj++) bV[jj] = U[base + jj * 132];
            }
            if (nt2 == 0) O0 = __builtin_amdgcn_mfma_f32_16x16x32_bf16(aP, bV, O0, 0, 0, 0);
            else          O1 = __builtin_amdgcn_mfma_f32_16x16x32_bf16(aP, bV, O1, 0, 0, 0);
        }
    }
    // ---- ao -> aoL (disjoint per-wave channel columns, no barrier needed) ----
#pragma unroll
    for (int r = 0; r < 4; r++) {
        const int m = quad * 4 + r;
        aoL[m * 136 + h * HD + l15] = f2bs(O0[r]);
        aoL[m * 136 + h * HD + 16 + l15] = f2bs(O1[r]);
    }
    __syncthreads();
    // ---- proj + fp32 residual -> out (x1) ----
    bf16x8 aO[4];
#pragma unroll
    for (int kt = 0; kt < 4; kt++)
        aO[kt] = *(const bf16x8*)&aoL[l15 * 136 + kt * 32 + quad * 8];
    f32x4 a0 = {0.f, 0.f, 0.f, 0.f}, a1 = {0.f, 0.f, 0.f, 0.f};
#pragma unroll
    for (int kt = 0; kt < 4; kt++) {
        bf16x8 b0 = *(const bf16x8*)&wproj[nR0 * C + kt * 32 + quad * 8];
        bf16x8 b1 = *(const bf16x8*)&wproj[nR1 * C + kt * 32 + quad * 8];
        a0 = __builtin_amdgcn_mfma_f32_16x16x32_bf16(aO[kt], b0, a0, 0, 0, 0);
        a1 = __builtin_amdgcn_mfma_f32_16x16x32_bf16(aO[kt], b1, a1, 0, 0, 0);
    }
    const float b0s = proj_b[nR0], b1s = proj_b[nR1];
#pragma unroll
    for (int r = 0; r < 4; r++) {
        const int m = quad * 4 + r;
        const int p = (i0 + (m >> 2)) * HW + j0 + (m & 3);
        out[(size_t)p * C + nR0] = xres0[r] + a0[r] + b0s;
        out[(size_t)p * C + nR1] = xres1[r] + a1[r] + b1s;
    }
}

// ---------- kernel 3: LN2 + fc1 + gelu + fc2 + residual (in-place on out) ----
__global__ __launch_bounds__(256, 4) void k_mlp(
    const float* __restrict__ n2_w, const float* __restrict__ n2_b,
    const short* __restrict__ wfc1, const float* __restrict__ fc1_b,
    const short* __restrict__ wfc2, const float* __restrict__ fc2_b,
    float* __restrict__ out) {
    __shared__ float x1l[16][132];
    __shared__ short xnb[16][136];
    __shared__ short hb[16 * 520];
    __shared__ float muA[16], riA[16];
    const int t = threadIdx.x;
    const int pix0 = (blockIdx.x & 7) * 2048 + (blockIdx.x >> 3) * 16;
    for (int e = t; e < 512; e += 256) {
        const int r = e >> 5, c4 = (e & 31) * 4;
        *(float4*)&x1l[r][c4] = *(const float4*)(out + (size_t)(pix0 + r) * C + c4);
    }
    __syncthreads();
    if (t < 128) {
        const int r = t >> 3, s = t & 7;
        float sm = 0.f, sq = 0.f;
        for (int i = 0; i < 16; i++) { float v = x1l[r][s * 16 + i]; sm += v; sq += v * v; }
        for (int m = 1; m < 8; m <<= 1) { sm += __shfl_xor(sm, m, 64); sq += __shfl_xor(sq, m, 64); }
        if (s == 0) {
            const float mu = sm * (1.f / 128.f);
            const float var = sq * (1.f / 128.f) - mu * mu;
            muA[r] = mu; riA[r] = rsqrtf(var + 1e-5f);
        }
    }
    __syncthreads();
    for (int e = t; e < 2048; e += 256) {
        const int r = e >> 7, c = e & 127;
        xnb[r][c] = f2bs((x1l[r][c] - muA[r]) * riA[r] * n2_w[c] + n2_b[c]);
    }
    __syncthreads();
    const int wave = t >> 6, lane = t & 63, quad = lane >> 4, l15 = lane & 15;
    // fc1 + gelu: 32 n-tiles over 4 waves
    {
        bf16x8 aX[4];
#pragma unroll
        for (int kt = 0; kt < 4; kt++)
            aX[kt] = *(const bf16x8*)&xnb[l15][kt * 32 + quad * 8];
#pragma unroll
        for (int a = 0; a < 8; a++) {
            const int n = (wave * 8 + a) * 16 + l15;
            f32x4 acc = {0.f, 0.f, 0.f, 0.f};
#pragma unroll
            for (int kt = 0; kt < 4; kt++) {
                bf16x8 bw = *(const bf16x8*)&wfc1[n * C + kt * 32 + quad * 8];
                acc = __builtin_amdgcn_mfma_f32_16x16x32_bf16(aX[kt], bw, acc, 0, 0, 0);
            }
            const float bias = fc1_b[n];
#pragma unroll
            for (int r = 0; r < 4; r++) {
                const int m = quad * 4 + r;
                hb[m * 520 + n] = f2bs(gelu_f(acc[r] + bias));
            }
        }
    }
    __syncthreads();
    // fc2 + fp32 residual
    {
        const int n0 = (wave * 2) * 16 + l15, n1 = (wave * 2 + 1) * 16 + l15;
        f32x4 a0 = {0.f, 0.f, 0.f, 0.f}, a1 = {0.f, 0.f, 0.f, 0.f};
#pragma unroll
        for (int kt = 0; kt < 16; kt++) {
            const bf16x8 aP = *(const bf16x8*)&hb[l15 * 520 + kt * 32 + quad * 8];
            bf16x8 b0 = *(const bf16x8*)&wfc2[n0 * 512 + kt * 32 + quad * 8];
            bf16x8 b1 = *(const bf16x8*)&wfc2[n1 * 512 + kt * 32 + quad * 8];
            a0 = __builtin_amdgcn_mfma_f32_16x16x32_bf16(aP, b0, a0, 0, 0, 0);
            a1 = __builtin_amdgcn_mfma_f32_16x16x32_bf16(aP, b1, a1, 0, 0, 0);
        }
        const float b0s = fc2_b[n0], b1s = fc2_b[n1];
#pragma unroll
        for (int r = 0; r < 4; r++) {
            const int m = quad * 4 + r;
            out[(size_t)(pix0 + m) * C + n0] = a0[r] + b0s + x1l[m][n0];
            out[(size_t)(pix0 + m) * C + n1] = a1[r] + b1s + x1l[m][n1];
        }
    }
}

extern "C" void kernel_launch(void* const* d_in, const int* in_sizes, int n_in,
                              void* d_out, int out_size, void* d_ws, size_t ws_size,
                              hipStream_t stream) {
    const float* x      = (const float*)d_in[0];
    const float* y      = (const float*)d_in[1];
    const float* qv_w   = (const float*)d_in[2];
    const float* qv_b   = (const float*)d_in[3];
    const float* k_w    = (const float*)d_in[4];
    const float* k_b    = (const float*)d_in[5];
    const float* rpb    = (const float*)d_in[6];
    const float* proj_w = (const float*)d_in[7];
    const float* proj_b = (const float*)d_in[8];
    const float* n1_w   = (const float*)d_in[9];
    const float* n1_b   = (const float*)d_in[10];
    const float* n2_w   = (const float*)d_in[11];
    const float* n2_b   = (const float*)d_in[12];
    const float* fc1_w  = (const float*)d_in[13];
    const float* fc1_b  = (const float*)d_in[14];
    const float* fc2_w  = (const float*)d_in[15];
    const float* fc2_b  = (const float*)d_in[16];
    float* out = (float*)d_out;

    bf16* qb  = (bf16*)d_ws;
    bf16* vb  = qb + (size_t)N_PIX * C;
    bf16* kb  = vb + (size_t)N_PIX * C;
    short* wqv  = (short*)(kb + (size_t)N_PIX * C); // 32768
    short* wk   = wqv + 32768;                      // 16384
    short* wproj= wk + 16384;                       // 16384
    short* wfc1 = wproj + 16384;                    // 65536
    short* wfc2 = wfc1 + 65536;                     // 65536  (total ~12.4 MB)

    k_wconv<<<256, 256, 0, stream>>>(qv_w, k_w, proj_w, fc1_w, fc2_w,
                                     wqv, wk, wproj, wfc1, wfc2);
    k_qkv<<<1024, 256, 0, stream>>>(x, y, wqv, qv_b, wk, k_b, n1_w, n1_b,
                                    qb, vb, kb);
    k_attn<<<1024, 256, 0, stream>>>(qb, kb, vb, rpb, x, wproj, proj_b, out);
    k_mlp<<<1024, 256, 0, stream>>>(n2_w, n2_b, wfc1, fc1_b, wfc2, fc2_b, out);
}

// Round 2
// 160.121 us; speedup vs baseline: 1.1079x; 1.1079x over previous
//
#include <hip/hip_runtime.h>
#include <hip/hip_bf16.h>

// CrossNATBlock2D: B=1, H=W=128, C=128, HEADS=4, HD=32, K=7  (fp32 I/O)
// R19: recombination. Keep R18's 16-px/256-thr k_qkv (the win); restore R0's
// fused k_fam (attn+proj+LN2+MLP in one kernel, 32px/512thr, proven 52.5us)
// instead of the split k_attn/k_mlp (the regression: x1 HBM round-trip +
// doubled halo). k_fam residual now reads fp32 x directly (xb copy deleted);
// x1 carried phase6->phase10 in fp32 registers (exact residual, fewer LDS ops).

#define N_PIX 16384
#define C 128
#define HEADS 4
#define HD 32
#define HW 128

typedef __hip_bfloat16 bf16;
typedef __attribute__((ext_vector_type(8))) short bf16x8;
typedef __attribute__((ext_vector_type(4))) float f32x4;

__device__ __forceinline__ short f2bs(float f) {
    bf16 h = __float2bfloat16(f);
    return (short)__bfloat16_as_ushort(h);
}
__device__ __forceinline__ float bs2f(short s) {
    __hip_bfloat16_raw r; r.x = (unsigned short)s;
    return __bfloat162float(__hip_bfloat16(r));
}
__device__ __forceinline__ float gelu_f(float v) {
    const float z = 1.5957691216f * (v + 0.044715f * v * v * v);
    return v / (1.f + __expf(-z));
}
__device__ __forceinline__ unsigned int pack2(float a, float b) {
    return (unsigned int)(unsigned short)f2bs(a) |
           ((unsigned int)(unsigned short)f2bs(b) << 16);
}

// ---------- kernel 0: convert weights fp32 -> bf16 into ws ----------
__global__ __launch_bounds__(256) void k_wconv(
    const float* __restrict__ qv_w, const float* __restrict__ k_w,
    const float* __restrict__ proj_w, const float* __restrict__ fc1_w,
    const float* __restrict__ fc2_w,
    short* __restrict__ wqv, short* __restrict__ wk, short* __restrict__ wproj,
    short* __restrict__ wfc1, short* __restrict__ wfc2) {
    const int i = blockIdx.x * 256 + threadIdx.x;
    if (i < 32768) wqv[i] = f2bs(qv_w[i]);
    if (i < 16384) { wk[i] = f2bs(k_w[i]); wproj[i] = f2bs(proj_w[i]); }
    if (i < 65536) { wfc1[i] = f2bs(fc1_w[i]); wfc2[i] = f2bs(fc2_w[i]); }
}

// ---------- kernel 1: LN1 + QV GEMM + K proj, 16 px/block, 256 thr ----------
__global__ __launch_bounds__(256, 4) void k_qkv(
    const float* __restrict__ x, const float* __restrict__ y,
    const short* __restrict__ wqv, const float* __restrict__ qv_b,
    const short* __restrict__ wk, const float* __restrict__ k_b,
    const float* __restrict__ n1_w, const float* __restrict__ n1_b,
    bf16* __restrict__ qb, bf16* __restrict__ vb, bf16* __restrict__ kb) {
    __shared__ float xr[16][132];
    __shared__ short xn[16][136];
    __shared__ short yl[16][136];
    __shared__ float muA[16], riA[16];
    const int t = threadIdx.x;
    const int pix0 = (blockIdx.x & 7) * 2048 + (blockIdx.x >> 3) * 16;
    for (int e = t; e < 512; e += 256) {           // 16 rows x 32 float4 groups
        const int r = e >> 5, c4 = (e & 31) * 4;
        const float4 xv = *(const float4*)(x + (size_t)(pix0 + r) * C + c4);
        *(float4*)&xr[r][c4] = xv;
        const float4 yv = *(const float4*)(y + (size_t)(pix0 + r) * C + c4);
        uint2 yp; yp.x = pack2(yv.x, yv.y); yp.y = pack2(yv.z, yv.w);
        *(uint2*)&yl[r][c4] = yp;
    }
    __syncthreads();
    if (t < 128) {
        const int r = t >> 3, s = t & 7;
        float sm = 0.f, sq = 0.f;
        for (int i = 0; i < 16; i++) { float v = xr[r][s * 16 + i]; sm += v; sq += v * v; }
        for (int m = 1; m < 8; m <<= 1) { sm += __shfl_xor(sm, m, 64); sq += __shfl_xor(sq, m, 64); }
        if (s == 0) {
            const float mu = sm * (1.f / 128.f);
            const float var = sq * (1.f / 128.f) - mu * mu;
            muA[r] = mu; riA[r] = rsqrtf(var + 1e-5f);
        }
    }
    __syncthreads();
    for (int e = t; e < 2048; e += 256) {
        const int r = e >> 7, c = e & 127;
        xn[r][c] = f2bs((xr[r][c] - muA[r]) * riA[r] * n1_w[c] + n1_b[c]);
    }
    __syncthreads();
    const int wave = t >> 6, lane = t & 63, quad = lane >> 4, l15 = lane & 15;
    const float scale = 0.1767766952966369f;   // 1/sqrt(32)
    // qv GEMM: M=16, 16 n-tiles over 4 waves
    {
        bf16x8 aA[4];
#pragma unroll
        for (int kt = 0; kt < 4; kt++)
            aA[kt] = *(const bf16x8*)&xn[l15][kt * 32 + quad * 8];
#pragma unroll
        for (int s = 0; s < 4; s++) {
            const int n = (wave * 4 + s) * 16 + l15;
            f32x4 acc = {0.f, 0.f, 0.f, 0.f};
#pragma unroll
            for (int kt = 0; kt < 4; kt++) {
                bf16x8 b = *(const bf16x8*)&wqv[n * C + kt * 32 + quad * 8];
                acc = __builtin_amdgcn_mfma_f32_16x16x32_bf16(aA[kt], b, acc, 0, 0, 0);
            }
            const float bias = qv_b[n];
#pragma unroll
            for (int r = 0; r < 4; r++) {
                const int m = quad * 4 + r;
                const float v = acc[r] + bias;
                if (n < C) qb[(size_t)(pix0 + m) * C + n] = __float2bfloat16(v * scale);
                else       vb[(size_t)(pix0 + m) * C + (n - C)] = __float2bfloat16(v);
            }
        }
    }
    // k GEMM: 8 n-tiles over 4 waves, 2 each, interleaved accumulators
    {
        bf16x8 aY[4];
#pragma unroll
        for (int kt = 0; kt < 4; kt++)
            aY[kt] = *(const bf16x8*)&yl[l15][kt * 32 + quad * 8];
        const int n0 = (wave * 2) * 16 + l15, n1 = (wave * 2 + 1) * 16 + l15;
        f32x4 a0 = {0.f, 0.f, 0.f, 0.f}, a1 = {0.f, 0.f, 0.f, 0.f};
#pragma unroll
        for (int kt = 0; kt < 4; kt++) {
            bf16x8 b0 = *(const bf16x8*)&wk[n0 * C + kt * 32 + quad * 8];
            bf16x8 b1 = *(const bf16x8*)&wk[n1 * C + kt * 32 + quad * 8];
            a0 = __builtin_amdgcn_mfma_f32_16x16x32_bf16(aY[kt], b0, a0, 0, 0, 0);
            a1 = __builtin_amdgcn_mfma_f32_16x16x32_bf16(aY[kt], b1, a1, 0, 0, 0);
        }
        const float b0s = k_b[n0], b1s = k_b[n1];
#pragma unroll
        for (int r = 0; r < 4; r++) {
            const int m = quad * 4 + r;
            kb[(size_t)(pix0 + m) * C + n0] = __float2bfloat16(a0[r] + b0s);
            kb[(size_t)(pix0 + m) * C + n1] = __float2bfloat16(a1[r] + b1s);
        }
    }
}

// ---------- kernel 2: fused attention + proj + residual + LN2 + MLP ----------
// 8x4 tile (32 px), 512 thr; wave = (mt<<2)|head. Union 14x10 = 140 rows.
__global__ __launch_bounds__(512, 2) void k_fam(
    const bf16* __restrict__ qb, const bf16* __restrict__ kb,
    const bf16* __restrict__ vb, const float* __restrict__ rpb,
    const float* __restrict__ x,
    const short* __restrict__ wproj, const float* __restrict__ proj_b,
    const float* __restrict__ n2_w, const float* __restrict__ n2_b,
    const short* __restrict__ wfc1, const float* __restrict__ fc1_b,
    const short* __restrict__ wfc2, const float* __restrict__ fc2_b,
    float* __restrict__ out) {
    __shared__ short KP[19008];   // K 140x132 -> P 128x144
    __shared__ short Vl[19008];   // V 140x132 -> hb
    __shared__ float muA[32], riA[32];
    short* const Pm  = KP;            // 128 x 144
    short* const aoL = KP;            // 32 x 136 (after PV)
    short* const x1b = KP + 4352;     // 32 x 136
    short* const xnb = KP + 8704;     // 32 x 136
    short* const hb  = Vl;            // 32 x 520
    const int t = threadIdx.x;
    const int wave = t >> 6, lane = t & 63, quad = lane >> 4, l15 = lane & 15;
    const int h = wave & 3, mt = wave >> 2;
    const int s_ = blockIdx.x >> 3;
    const int i0 = ((blockIdx.x & 7) * 2 + (s_ >> 5)) * 8;
    const int j0 = (s_ & 31) * 4;
    const int rs = min(max(i0 - 3, 0), 114);
    const int cs = min(max(j0 - 3, 0), 118);
    // ---- register prefetch (HBM latency overlaps staging below) ----
    const int mA = mt * 16 + l15;
    const int pA = (i0 + (mA >> 2)) * HW + j0 + (mA & 3);
    const bf16x8 aQ = *(const bf16x8*)(qb + (size_t)pA * C + h * HD + quad * 8);
    const int nR0 = h * 16 + l15, nR1 = (h + 4) * 16 + l15;
    float xres0[4], xres1[4];
#pragma unroll
    for (int r = 0; r < 4; r++) {
        const int m = mt * 16 + quad * 4 + r;
        const int p = (i0 + (m >> 2)) * HW + j0 + (m & 3);
        xres0[r] = x[(size_t)p * C + nR0];
        xres1[r] = x[(size_t)p * C + nR1];
    }
    // ---- phase 1: stage K,V unions (140 rows x 128 ch) ----
    for (int u = t; u < 140 * 16 * 2; u += 512) {
        const int tv = (u >= 2240) ? 1 : 0;
        const int uu = tv ? u - 2240 : u;
        const int r = uu >> 4, seg = uu & 15;
        const size_t g = (size_t)((rs + r / 10) * HW + cs + r % 10) * C + seg * 8;
        const uint4 d = *(const uint4*)((tv ? vb : kb) + g);
        *(uint4*)&(tv ? Vl : KP)[r * 132 + seg * 8] = d;
    }
    __syncthreads();
    // ---- phase 2: QK^T + bias/mask + softmax ----
    f32x4 S[9];
#pragma unroll
    for (int nt = 0; nt < 9; nt++) {
        const bf16x8 bK = *(const bf16x8*)&KP[(nt * 16 + l15) * 132 + h * HD + quad * 8];
        f32x4 z = {0.f, 0.f, 0.f, 0.f};
        S[nt] = __builtin_amdgcn_mfma_f32_16x16x32_bf16(aQ, bK, z, 0, 0, 0);
    }
    const float* rpbh = rpb + h * 169;
    float smx[4];
#pragma unroll
    for (int r = 0; r < 4; r++) {
        const int m = mt * 16 + quad * 4 + r;
        const int i = i0 + (m >> 2), j = j0 + (m & 3);
        const int shi = min(max(i - 3, 0), 121);
        const int swj = min(max(j - 3, 0), 121);
        float best = -1e30f;
#pragma unroll
        for (int nt = 0; nt < 9; nt++) {
            const int nb = nt * 16 + l15;
            const int ai = rs + nb / 10, aj = cs + nb % 10;
            const bool valid = (nb < 140) & (ai >= shi) & (ai <= shi + 6) & (aj >= swj) & (aj <= swj + 6);
            const int ri = min(max(ai - i + 6, 0), 12);
            const int rj = min(max(aj - j + 6, 0), 12);
            const float v = valid ? (S[nt][r] + rpbh[ri * 13 + rj]) : -1e30f;
            S[nt][r] = v;
            best = fmaxf(best, v);
        }
        for (int msk = 1; msk < 16; msk <<= 1) best = fmaxf(best, __shfl_xor(best, msk, 64));
        float s = 0.f;
#pragma unroll
        for (int nt = 0; nt < 9; nt++) {
            const float e = __expf(S[nt][r] - best);
            S[nt][r] = e;
            s += e;
        }
        for (int msk = 1; msk < 16; msk <<= 1) s += __shfl_xor(s, msk, 64);
        smx[r] = 1.f / s;
    }
    __syncthreads();   // all K reads done before P overwrites
    // ---- phase 3: P -> Pm (stride 144, own rows) ----
#pragma unroll
    for (int r = 0; r < 4; r++) {
        short* prow = &Pm[(wave * 16 + quad * 4 + r) * 144];
#pragma unroll
        for (int nt = 0; nt < 9; nt++)
            prow[nt * 16 + l15] = f2bs(S[nt][r] * smx[r]);
    }
    // NOTE: no barrier — PV reads only this wave's own 16 P rows (lgkmcnt
    // ordering within the wave is sufficient).
    // ---- phase 4: PV (kt 0..3 unpredicated; kt=4 peeled) ----
    f32x4 O0 = {0.f, 0.f, 0.f, 0.f}, O1 = {0.f, 0.f, 0.f, 0.f};
#pragma unroll
    for (int kt = 0; kt < 4; kt++) {
        const bf16x8 aP = *(const bf16x8*)&Pm[(wave * 16 + l15) * 144 + kt * 32 + quad * 8];
#pragma unroll
        for (int nt2 = 0; nt2 < 2; nt2++) {
            const int ch = h * HD + nt2 * 16 + l15;
            const int base = (kt * 32 + quad * 8) * 132 + ch;
            bf16x8 bV;
#pragma unroll
            for (int jj = 0; jj < 8; jj++) bV[jj] = Vl[base + jj * 132];
            if (nt2 == 0) O0 = __builtin_amdgcn_mfma_f32_16x16x32_bf16(aP, bV, O0, 0, 0, 0);
            else          O1 = __builtin_amdgcn_mfma_f32_16x16x32_bf16(aP, bV, O1, 0, 0, 0);
        }
    }
    {   // kt = 4: nbr 128..159; valid only 128..139
        const bf16x8 aP = *(const bf16x8*)&Pm[(wave * 16 + l15) * 144 + 128 + quad * 8];
#pragma unroll
        for (int nt2 = 0; nt2 < 2; nt2++) {
            const int ch = h * HD + nt2 * 16 + l15;
            bf16x8 bV = {0, 0, 0, 0, 0, 0, 0, 0};
            if (quad == 0) {
                const int base = 128 * 132 + ch;
#pragma unroll
                for (int jj = 0; jj < 8; jj++) bV[jj] = Vl[base + jj * 132];
            } else if (quad == 1) {
                const int base = 136 * 132 + ch;
#pragma unroll
                for (int jj = 0; jj < 4; jj++) bV[jj] = Vl[base + jj * 132];
            }
            if (nt2 == 0) O0 = __builtin_amdgcn_mfma_f32_16x16x32_bf16(aP, bV, O0, 0, 0, 0);
            else          O1 = __builtin_amdgcn_mfma_f32_16x16x32_bf16(aP, bV, O1, 0, 0, 0);
        }
    }
    __syncthreads();   // all P/V reads done; K/V regions now dead
    // ---- phase 5: ao -> aoL ----
#pragma unroll
    for (int r = 0; r < 4; r++) {
        const int m = mt * 16 + quad * 4 + r;
        aoL[m * 136 + h * HD + l15] = f2bs(O0[r]);
        aoL[m * 136 + h * HD + 16 + l15] = f2bs(O1[r]);
    }
    __syncthreads();
    // ---- phase 6: proj + fp32 residual -> x1b (+ fp32 kept in regs) ----
    float x1f0[4], x1f1[4];
    {
        bf16x8 aO[4];
#pragma unroll
        for (int kt = 0; kt < 4; kt++)
            aO[kt] = *(const bf16x8*)&aoL[(mt * 16 + l15) * 136 + kt * 32 + quad * 8];
        f32x4 a0 = {0.f, 0.f, 0.f, 0.f}, a1 = {0.f, 0.f, 0.f, 0.f};
#pragma unroll
        for (int kt = 0; kt < 4; kt++) {
            bf16x8 b0 = *(const bf16x8*)&wproj[nR0 * C + kt * 32 + quad * 8];
            bf16x8 b1 = *(const bf16x8*)&wproj[nR1 * C + kt * 32 + quad * 8];
            a0 = __builtin_amdgcn_mfma_f32_16x16x32_bf16(aO[kt], b0, a0, 0, 0, 0);
            a1 = __builtin_amdgcn_mfma_f32_16x16x32_bf16(aO[kt], b1, a1, 0, 0, 0);
        }
        const float b0s = proj_b[nR0], b1s = proj_b[nR1];
#pragma unroll
        for (int r = 0; r < 4; r++) {
            const int m = mt * 16 + quad * 4 + r;
            const float v0 = xres0[r] + a0[r] + b0s;
            const float v1 = xres1[r] + a1[r] + b1s;
            x1f0[r] = v0; x1f1[r] = v1;
            x1b[m * 136 + nR0] = f2bs(v0);
            x1b[m * 136 + nR1] = f2bs(v1);
        }
    }
    __syncthreads();
    // ---- phase 7: LN2 stats ----
    if (t < 256) {
        const int r = t >> 3, s = t & 7;
        float sm = 0.f, sq = 0.f;
        for (int i = 0; i < 16; i++) { float v = bs2f(x1b[r * 136 + s * 16 + i]); sm += v; sq += v * v; }
        for (int m = 1; m < 8; m <<= 1) { sm += __shfl_xor(sm, m, 64); sq += __shfl_xor(sq, m, 64); }
        if (s == 0) {
            const float mu = sm * (1.f / 128.f);
            const float var = sq * (1.f / 128.f) - mu * mu;
            muA[r] = mu; riA[r] = rsqrtf(var + 1e-5f);
        }
    }
    __syncthreads();
    // ---- phase 8: xn = LN(x1) -> xnb ----
    for (int e = t; e < 32 * 128; e += 512) {
        const int r = e >> 7, c = e & 127;
        xnb[r * 136 + c] = f2bs((bs2f(x1b[r * 136 + c]) - muA[r]) * riA[r] * n2_w[c] + n2_b[c]);
    }
    __syncthreads();
    // ---- phase 9: fc1 + gelu -> hb ----
    {
        bf16x8 aX[4];
#pragma unroll
        for (int kt = 0; kt < 4; kt++)
            aX[kt] = *(const bf16x8*)&xnb[(mt * 16 + l15) * 136 + kt * 32 + quad * 8];
#pragma unroll
        for (int a = 0; a < 4; a++) {
            const int n0 = (h + 8 * a) * 16 + l15, n1 = (h + 8 * a + 4) * 16 + l15;
            f32x4 a0 = {0.f, 0.f, 0.f, 0.f}, a1 = {0.f, 0.f, 0.f, 0.f};
#pragma unroll
            for (int kt = 0; kt < 4; kt++) {
                bf16x8 b0 = *(const bf16x8*)&wfc1[n0 * C + kt * 32 + quad * 8];
                bf16x8 b1 = *(const bf16x8*)&wfc1[n1 * C + kt * 32 + quad * 8];
                a0 = __builtin_amdgcn_mfma_f32_16x16x32_bf16(aX[kt], b0, a0, 0, 0, 0);
                a1 = __builtin_amdgcn_mfma_f32_16x16x32_bf16(aX[kt], b1, a1, 0, 0, 0);
            }
            const float b0s = fc1_b[n0], b1s = fc1_b[n1];
#pragma unroll
            for (int r = 0; r < 4; r++) {
                const int m = mt * 16 + quad * 4 + r;
                hb[m * 520 + n0] = f2bs(gelu_f(a0[r] + b0s));
                hb[m * 520 + n1] = f2bs(gelu_f(a1[r] + b1s));
            }
        }
    }
    __syncthreads();
    // ---- phase 10: fc2 + fp32 residual (registers) -> out ----
    {
        f32x4 a0 = {0.f, 0.f, 0.f, 0.f}, a1 = {0.f, 0.f, 0.f, 0.f};
#pragma unroll
        for (int kt = 0; kt < 16; kt++) {
            const bf16x8 aP = *(const bf16x8*)&hb[(mt * 16 + l15) * 520 + kt * 32 + quad * 8];
            bf16x8 b0 = *(const bf16x8*)&wfc2[nR0 * 512 + kt * 32 + quad * 8];
            bf16x8 b1 = *(const bf16x8*)&wfc2[nR1 * 512 + kt * 32 + quad * 8];
            a0 = __builtin_amdgcn_mfma_f32_16x16x32_bf16(aP, b0, a0, 0, 0, 0);
            a1 = __builtin_amdgcn_mfma_f32_16x16x32_bf16(aP, b1, a1, 0, 0, 0);
        }
        const float b0s = fc2_b[nR0], b1s = fc2_b[nR1];
#pragma unroll
        for (int r = 0; r < 4; r++) {
            const int m = mt * 16 + quad * 4 + r;
            const int p = (i0 + (m >> 2)) * HW + j0 + (m & 3);
            out[(size_t)p * C + nR0] = a0[r] + b0s + x1f0[r];
            out[(size_t)p * C + nR1] = a1[r] + b1s + x1f1[r];
        }
    }
}

extern "C" void kernel_launch(void* const* d_in, const int* in_sizes, int n_in,
                              void* d_out, int out_size, void* d_ws, size_t ws_size,
                              hipStream_t stream) {
    const float* x      = (const float*)d_in[0];
    const float* y      = (const float*)d_in[1];
    const float* qv_w   = (const float*)d_in[2];
    const float* qv_b   = (const float*)d_in[3];
    const float* k_w    = (const float*)d_in[4];
    const float* k_b    = (const float*)d_in[5];
    const float* rpb    = (const float*)d_in[6];
    const float* proj_w = (const float*)d_in[7];
    const float* proj_b = (const float*)d_in[8];
    const float* n1_w   = (const float*)d_in[9];
    const float* n1_b   = (const float*)d_in[10];
    const float* n2_w   = (const float*)d_in[11];
    const float* n2_b   = (const float*)d_in[12];
    const float* fc1_w  = (const float*)d_in[13];
    const float* fc1_b  = (const float*)d_in[14];
    const float* fc2_w  = (const float*)d_in[15];
    const float* fc2_b  = (const float*)d_in[16];
    float* out = (float*)d_out;

    bf16* qb  = (bf16*)d_ws;
    bf16* vb  = qb + (size_t)N_PIX * C;
    bf16* kb  = vb + (size_t)N_PIX * C;
    short* wqv  = (short*)(kb + (size_t)N_PIX * C); // 32768
    short* wk   = wqv + 32768;                      // 16384
    short* wproj= wk + 16384;                       // 16384
    short* wfc1 = wproj + 16384;                    // 65536
    short* wfc2 = wfc1 + 65536;                     // 65536  (total ~12.4 MB)

    k_wconv<<<256, 256, 0, stream>>>(qv_w, k_w, proj_w, fc1_w, fc2_w,
                                     wqv, wk, wproj, wfc1, wfc2);
    k_qkv<<<1024, 256, 0, stream>>>(x, y, wqv, qv_b, wk, k_b, n1_w, n1_b,
                                    qb, vb, kb);
    k_fam<<<512, 512, 0, stream>>>(qb, kb, vb, rpb, x, wproj, proj_b, n2_w, n2_b,
                                   wfc1, fc1_b, wfc2, fc2_b, out);
}